// Round 9
// baseline (115.191 us; speedup 1.0000x reference)
//
#include <hip/hip_runtime.h>
#include <math.h>

#define NB 32    // batch
#define NS 128   // steps
#define NI 256   // in_dim
#define NC 128   // num capsules
#define ND 64    // dim capsule

#define L4 9.210340371976184f  // ln(10000)

// ---------------------------------------------------------------------------
// k_prep:
//   blocks [0,1024):      M[b,s,d] = sum_i u*W ; U[b,s] = sum_i u
//   blocks [1024,1056):   PE1[n][d]
// ---------------------------------------------------------------------------
__global__ __launch_bounds__(256) void k_prep(const float* __restrict__ u,
                                              const float* __restrict__ W,
                                              float* __restrict__ M,
                                              float* __restrict__ U,
                                              float* __restrict__ PE1) {
    int blk = blockIdx.x;
    int t = threadIdx.x;
    if (blk < 1024) {
        int row = blk * 4 + (t >> 6);   // b*NS + s
        int d = t & 63;
        const float* ur = u + row * NI;
        float acc = 0.f, rs = 0.f;
#pragma unroll 4
        for (int i = 0; i < NI; ++i) {
            float v = ur[i];
            acc = fmaf(v, W[i * ND + d], acc);
            rs += v;
        }
        M[row * ND + d] = acc;
        if (d == 0) U[row] = rs;
    } else {
        int idx = (blk - 1024) * 256 + t;   // 8192 elems, [n][d]
        int n = idx >> 6, d = idx & 63;
        float ang = (float)n * __expf(-L4 * (float)(d >> 1) * (1.f / 32.f));
        float sv, cv;
        __sincosf(ang, &sv, &cv);
        PE1[idx] = (d & 1) ? cv : sv;
    }
}

// ---------------------------------------------------------------------------
// kR v5: one routing iteration, one block per (b,n). 256 threads, ~10.3 KB
// LDS. Thread (sq=t>>4, dq=t&15) owns s in [sq*8, sq*8+8) x d-quad dq.
// pe2 trig via ROTATION RECURRENCE: sin/cos(s*g) for 8 consecutive s from
// one native-init pair + 8 fma/iter — replaces 16 libm __sincosf calls
// (large-arg range reduction ~60 instr each) that dominated kR v4.
//   staging: cs[s]; T2 = sum_s c*U via wave shfl (pe1*U folded out).
//   pass 1: v = M4 + pe2 (registers); acc += c[s]*v; shfl+LDS reduce;
//           16-lane tail adds pe1*T2, squash, PUu = sum outp*pe1.
//   pass 2: dot(v, outs4[dq]) -> red2[s*17+dq] (2-way banks, free);
//           128 threads sum 16 partials + PUu*U[s]; coalesced bl store.
// grid = 4096. Global traffic: M once (134 MB/launch, L2-resident).
// ---------------------------------------------------------------------------
__global__ __launch_bounds__(256) void kR(const float* __restrict__ M,
                                          const float* __restrict__ U,
                                          const float* __restrict__ PE1,
                                          const float* __restrict__ cg,
                                          const float* __restrict__ mask,
                                          float* __restrict__ og,
                                          float* __restrict__ bl,
                                          int first, int last) {
    int bn = blockIdx.x;
    int b = bn >> 7, n = bn & 127;
    int t = threadIdx.x;

    __shared__ float  cs[NS];           //  512 B
    __shared__ float4 redw[4][16];      // 1024 B
    __shared__ float4 outs4[16];        //  256 B
    __shared__ float  tpar[2];          // T2 wave-partials
    __shared__ float  sc2[2];           // {scale, PUu}
    __shared__ float  red2[NS * 17];    // 8704 B

    // ---- staging: c, and T2 = sum_s c*U (wave-level reduce, waves 0-1) ----
    if (t < NS) {
        float cv = first ? mask[b * NS + t] * (1.f / 128.f) : cg[bn * NS + t];
        cs[t] = cv;
        float p = cv * U[b * NS + t];
#pragma unroll
        for (int o = 32; o > 0; o >>= 1) p += __shfl_xor(p, o);
        if ((t & 63) == 0) tpar[t >> 6] = p;
    }

    int dq = t & 15, sq = t >> 4;
    int s0 = sq * 8;
    // pe2 frequencies for this (n, d-quad): two (sin,cos) pairs
    int k2 = n * 32 + dq * 2;
    float g0 = __expf(-L4 * (float)k2 * (1.f / 4096.f));
    float g1 = __expf(-L4 * (float)(k2 + 1) * (1.f / 4096.f));
    // rotation-recurrence state: sin/cos(s0*g), step sin/cos(g). Native
    // v_sin/v_cos (rev = x/2pi <= 20.2, inside HW wrap domain).
    float sa = __sinf((float)s0 * g0), ca = __cosf((float)s0 * g0);
    float sb = __sinf((float)s0 * g1), cb = __cosf((float)s0 * g1);
    float sg0 = __sinf(g0), cg0 = __cosf(g0);
    float sg1 = __sinf(g1), cg1 = __cosf(g1);
    __syncthreads();

    // ---- pass 1: build v = M + pe2 (registers), acc += c*v ----
    const float4* M4 = (const float4*)(M + (size_t)(b * NS) * ND) + dq;
    float4 v[8];
    float4 acc = make_float4(0.f, 0.f, 0.f, 0.f);
#pragma unroll
    for (int i = 0; i < 8; ++i) {
        int s = s0 + i;
        float4 m4 = M4[s * 16];
        float4 vv;
        vv.x = m4.x + sa; vv.y = m4.y + ca;
        vv.z = m4.z + sb; vv.w = m4.w + cb;
        v[i] = vv;
        float cc = cs[s];
        acc.x = fmaf(cc, vv.x, acc.x);
        acc.y = fmaf(cc, vv.y, acc.y);
        acc.z = fmaf(cc, vv.z, acc.z);
        acc.w = fmaf(cc, vv.w, acc.w);
        // rotate to s+1: (sa,ca) *= e^{i g0}, (sb,cb) *= e^{i g1}
        float nsa = fmaf(sa, cg0, ca * sg0);
        float nca = fmaf(ca, cg0, -sa * sg0);
        sa = nsa; ca = nca;
        float nsb = fmaf(sb, cg1, cb * sg1);
        float ncb = fmaf(cb, cg1, -sb * sg1);
        sb = nsb; cb = ncb;
    }
    // reduce the 4 sq-chunks within each wave (lanes xor 16, 32)
#pragma unroll
    for (int o = 16; o <= 32; o <<= 1) {
        acc.x += __shfl_xor(acc.x, o);
        acc.y += __shfl_xor(acc.y, o);
        acc.z += __shfl_xor(acc.z, o);
        acc.w += __shfl_xor(acc.w, o);
    }
    if ((t & 48) == 0) redw[t >> 6][dq] = acc;   // one writer per (wave, dq)
    __syncthreads();

    // ---- combine + squash (wave 0, lanes 0-15) ----
    if (t < 16) {
        float4 r0 = redw[0][t], r1 = redw[1][t], r2 = redw[2][t], r3 = redw[3][t];
        float4 o;
        o.x = r0.x + r1.x + r2.x + r3.x;
        o.y = r0.y + r1.y + r2.y + r3.y;
        o.z = r0.z + r1.z + r2.z + r3.z;
        o.w = r0.w + r1.w + r2.w + r3.w;
        float T2 = tpar[0] + tpar[1];
        float4 p14 = ((const float4*)PE1)[n * 16 + t];
        o.x = fmaf(p14.x, T2, o.x);
        o.y = fmaf(p14.y, T2, o.y);
        o.z = fmaf(p14.z, T2, o.z);
        o.w = fmaf(p14.w, T2, o.w);
        outs4[t] = o;                    // pre-squash out_pre
        float ssq = o.x * o.x + o.y * o.y + o.z * o.z + o.w * o.w;
        float ppu = o.x * p14.x + o.y * p14.y + o.z * p14.z + o.w * p14.w;
#pragma unroll
        for (int o2 = 1; o2 <= 8; o2 <<= 1) {
            ssq += __shfl_xor(ssq, o2);
            ppu += __shfl_xor(ppu, o2);
        }
        if (t == 0) {
            sc2[0] = ssq / (1.f + ssq) * rsqrtf(ssq + 1e-7f);
            sc2[1] = ppu;
        }
    }
    __syncthreads();
    float scale = sc2[0];

    if (last) {
        if (t < 16) {
            float4 o = outs4[t];
            o.x *= scale; o.y *= scale; o.z *= scale; o.w *= scale;
            ((float4*)og)[bn * 16 + t] = o;
        }
        return;
    }

    // ---- pass 2: bl[s] = scale*(sum_d outp*(M+pe2) + PUu*U[s]) ----
    float4 o4 = outs4[dq];
#pragma unroll
    for (int i = 0; i < 8; ++i) {
        int s = s0 + i;
        float4 vv = v[i];
        red2[s * 17 + dq] = vv.x * o4.x + vv.y * o4.y + vv.z * o4.z + vv.w * o4.w;
    }
    __syncthreads();
    if (t < NS) {
        const float* r = red2 + t * 17;
        float sum = 0.f;
#pragma unroll
        for (int q = 0; q < 16; ++q) sum += r[q];
        bl[bn * NS + t] = scale * (sum + sc2[1] * U[b * NS + t]);
    }
}

// ---------------------------------------------------------------------------
// kS: softmax over n for each (b,s); c[b,n,s] = softmax_n(bl[b,n,s])*mask.
// bl/c layout [b][n][s]. Block = (b, 16-s tile), 256 thr. grid = 256.
// ---------------------------------------------------------------------------
__global__ __launch_bounds__(256) void kS(const float* __restrict__ bl,
                                          const float* __restrict__ mask,
                                          float* __restrict__ c) {
    int blk = blockIdx.x;
    int b = blk >> 3, s0 = (blk & 7) * 16;
    int t = threadIdx.x;

    __shared__ float tl[NC][17];
    __shared__ float pr[16][17];
    __shared__ float ps[16][17];
    __shared__ float itot[16], msk[16];

    if (t < 16) msk[t] = mask[b * NS + s0 + t];
#pragma unroll
    for (int i = 0; i < 8; ++i) {
        int idx = i * 256 + t;
        int n = idx >> 4, si = idx & 15;
        tl[n][si] = bl[(b * NC + n) * NS + s0 + si];
    }
    __syncthreads();

    int si = t & 15, ch = t >> 4;      // 16 chunks x 8 n each
    float mx = -1e30f;
#pragma unroll
    for (int j = 0; j < 8; ++j) mx = fmaxf(mx, tl[ch * 8 + j][si]);
    pr[ch][si] = mx;
    __syncthreads();

    mx = pr[0][si];
#pragma unroll
    for (int jc = 1; jc < 16; ++jc) mx = fmaxf(mx, pr[jc][si]);
    float sm = 0.f;
#pragma unroll
    for (int j = 0; j < 8; ++j) {
        float e = __expf(tl[ch * 8 + j][si] - mx);
        tl[ch * 8 + j][si] = e;       // owner-exclusive rows: no race
        sm += e;
    }
    ps[ch][si] = sm;
    __syncthreads();

    if (t < 16) {
        float tot = 0.f;
#pragma unroll
        for (int jc = 0; jc < 16; ++jc) tot += ps[jc][t];
        itot[t] = msk[t] / tot;
    }
    __syncthreads();

#pragma unroll
    for (int i = 0; i < 8; ++i) {
        int idx = i * 256 + t;
        int n = idx >> 4, sj = idx & 15;
        c[(b * NC + n) * NS + s0 + sj] = tl[n][sj] * itot[sj];
    }
}

// ---------------------------------------------------------------------------
extern "C" void kernel_launch(void* const* d_in, const int* in_sizes, int n_in,
                              void* d_out, int out_size, void* d_ws, size_t ws_size,
                              hipStream_t stream) {
    const float* u    = (const float*)d_in[0];  // (32,128,256)
    const float* mask = (const float*)d_in[1];  // (32,128)
    const float* W    = (const float*)d_in[2];  // (1,256,64)
    float* out = (float*)d_out;                 // (32,128,64) = [b][n][d]

    float* ws  = (float*)d_ws;
    float* M   = ws;                            // 262144
    float* U   = M + NB * NS * ND;              // 4096
    float* PE1 = U + NB * NS;                   // 8192
    float* c   = PE1 + NC * ND;                 // 524288  [b][n][s]
    float* bl  = c + NB * NC * NS;              // 524288  [b][n][s]

    k_prep<<<1056, 256, 0, stream>>>(u, W, M, U, PE1);

    // iter 0 (uniform c = mask/128) -> logits bl
    kR<<<NB * NC, 256, 0, stream>>>(M, U, PE1, c, mask, out, bl, 1, 0);
    kS<<<NB * 8, 256, 0, stream>>>(bl, mask, c);
    // iter 1 -> logits bl
    kR<<<NB * NC, 256, 0, stream>>>(M, U, PE1, c, mask, out, bl, 0, 0);
    kS<<<NB * 8, 256, 0, stream>>>(bl, mask, c);
    // iter 2 (final) -> d_out
    kR<<<NB * NC, 256, 0, stream>>>(M, U, PE1, c, mask, out, bl, 0, 1);
}

// Round 10
// 112.085 us; speedup vs baseline: 1.0277x; 1.0277x over previous
//
#include <hip/hip_runtime.h>
#include <math.h>

#define NB 32    // batch
#define NS 128   // steps
#define NI 256   // in_dim
#define NC 128   // num capsules
#define ND 64    // dim capsule

#define L4 9.210340371976184f  // ln(10000)

// ---------------------------------------------------------------------------
// k_prep:
//   blocks [0,1024):      M[b,s,d] = sum_i u*W ; U[b,s] = sum_i u
//   blocks [1024,1056):   PE1[n][d]
// ---------------------------------------------------------------------------
__global__ __launch_bounds__(256) void k_prep(const float* __restrict__ u,
                                              const float* __restrict__ W,
                                              float* __restrict__ M,
                                              float* __restrict__ U,
                                              float* __restrict__ PE1) {
    int blk = blockIdx.x;
    int t = threadIdx.x;
    if (blk < 1024) {
        int row = blk * 4 + (t >> 6);   // b*NS + s
        int d = t & 63;
        const float* ur = u + row * NI;
        float acc = 0.f, rs = 0.f;
#pragma unroll 4
        for (int i = 0; i < NI; ++i) {
            float v = ur[i];
            acc = fmaf(v, W[i * ND + d], acc);
            rs += v;
        }
        M[row * ND + d] = acc;
        if (d == 0) U[row] = rs;
    } else {
        int idx = (blk - 1024) * 256 + t;   // 8192 elems, [n][d]
        int n = idx >> 6, d = idx & 63;
        float ang = (float)n * __expf(-L4 * (float)(d >> 1) * (1.f / 32.f));
        float sv, cv;
        __sincosf(ang, &sv, &cv);
        PE1[idx] = (d & 1) ? cv : sv;
    }
}

// ---------------------------------------------------------------------------
// kR v6: one routing iteration, block = (2 batches, 1 capsule n).
// 256 threads, ~22 KB LDS, grid = 2048. Thread (sq=t>>4, dq=t&15) owns
// s in [sq*8, sq*8+8) x d-quad dq for BOTH batches: the pe2 rotation
// recurrence (identical for both b's at fixed (n,dq)) is computed ONCE and
// consumed twice — ~30% fewer VALU ops and 2x amortized staging/reductions
// vs the per-(b,n) v5.
//   staging: cs[s][bh], Us[s][bh]; T2[bh] = sum_s c*U via per-wave shfl.
//   pass 1: v{a,b}[i] = M + pe2(rotation, registers); acc{0,1} += c*v;
//           shfl reduce over sq-chunks; 32-lane tail: +pe1*T2, squash,
//           PUu = sum outp*pe1 (per bh).
//   pass 2: dot(v, outs4[bh][dq]) -> red2[bh][s*17+dq] (2-way banks, free);
//           256 threads (bh=t>>7) sum 16 partials + PUu*U; coalesced bl.
// ---------------------------------------------------------------------------
__global__ __launch_bounds__(256, 4) void kR(const float* __restrict__ M,
                                             const float* __restrict__ U,
                                             const float* __restrict__ PE1,
                                             const float* __restrict__ cg,
                                             const float* __restrict__ mask,
                                             float* __restrict__ og,
                                             float* __restrict__ bl,
                                             int first, int last) {
    int bp = blockIdx.x;                // (b-pair)*128 + n
    int n  = bp & 127;
    int b0 = (bp >> 7) * 2;
    int t  = threadIdx.x;

    __shared__ float  cs[NS][2];        // 1 KB  (c for b0, b0+1 packed)
    __shared__ float  Us[NS][2];        // 1 KB
    __shared__ float4 redw[2][4][16];   // 2 KB
    __shared__ float4 outs4[2][16];     // 512 B
    __shared__ float  tpar[2][2];
    __shared__ float  sc2[2][2];        // [bh][{scale, PUu}]
    __shared__ float  red2[2][NS * 17]; // 17408 B

    // ---- staging: c, U, and T2[bh] = sum_s c*U (one wave per 64 s) ----
    {
        int bh = t >> 7, s = t & 127;
        int b = b0 + bh;
        float uu = U[b * NS + s];
        float cv = first ? mask[b * NS + s] * (1.f / 128.f)
                         : cg[(b * NC + n) * NS + s];
        cs[s][bh] = cv;
        Us[s][bh] = uu;
        float p = cv * uu;
#pragma unroll
        for (int o = 32; o > 0; o >>= 1) p += __shfl_xor(p, o);
        if ((t & 63) == 0) tpar[bh][(t >> 6) & 1] = p;
    }

    int dq = t & 15, sq = t >> 4;
    int s0 = sq * 8;
    // pe2 frequencies for (n, dq) — shared by both batches
    int k2 = n * 32 + dq * 2;
    float g0 = __expf(-L4 * (float)k2 * (1.f / 4096.f));
    float g1 = __expf(-L4 * (float)(k2 + 1) * (1.f / 4096.f));
    float sa = __sinf((float)s0 * g0), ca = __cosf((float)s0 * g0);
    float sb = __sinf((float)s0 * g1), cb = __cosf((float)s0 * g1);
    float sg0 = __sinf(g0), cg0 = __cosf(g0);
    float sg1 = __sinf(g1), cg1 = __cosf(g1);
    __syncthreads();

    // ---- pass 1 ----
    const float4* M4a = (const float4*)(M + (size_t)(b0 * NS) * ND) + dq;
    const float4* M4b = M4a + NS * 16;
    float4 va[8], vb[8];
    float4 acc0 = make_float4(0.f, 0.f, 0.f, 0.f);
    float4 acc1 = make_float4(0.f, 0.f, 0.f, 0.f);
#pragma unroll
    for (int i = 0; i < 8; ++i) {
        int s = s0 + i;
        float4 m0 = M4a[s * 16];
        float4 m1 = M4b[s * 16];
        float2 cc = *(const float2*)&cs[s][0];
        float4 u0, u1;
        u0.x = m0.x + sa; u0.y = m0.y + ca; u0.z = m0.z + sb; u0.w = m0.w + cb;
        u1.x = m1.x + sa; u1.y = m1.y + ca; u1.z = m1.z + sb; u1.w = m1.w + cb;
        va[i] = u0; vb[i] = u1;
        acc0.x = fmaf(cc.x, u0.x, acc0.x);
        acc0.y = fmaf(cc.x, u0.y, acc0.y);
        acc0.z = fmaf(cc.x, u0.z, acc0.z);
        acc0.w = fmaf(cc.x, u0.w, acc0.w);
        acc1.x = fmaf(cc.y, u1.x, acc1.x);
        acc1.y = fmaf(cc.y, u1.y, acc1.y);
        acc1.z = fmaf(cc.y, u1.z, acc1.z);
        acc1.w = fmaf(cc.y, u1.w, acc1.w);
        // rotate both frequency pairs to s+1
        float nsa = fmaf(sa, cg0, ca * sg0);
        float nca = fmaf(ca, cg0, -sa * sg0);
        sa = nsa; ca = nca;
        float nsb = fmaf(sb, cg1, cb * sg1);
        float ncb = fmaf(cb, cg1, -sb * sg1);
        sb = nsb; cb = ncb;
    }
    // reduce the 4 sq-chunks within each wave (lanes xor 16, 32)
#pragma unroll
    for (int o = 16; o <= 32; o <<= 1) {
        acc0.x += __shfl_xor(acc0.x, o); acc0.y += __shfl_xor(acc0.y, o);
        acc0.z += __shfl_xor(acc0.z, o); acc0.w += __shfl_xor(acc0.w, o);
        acc1.x += __shfl_xor(acc1.x, o); acc1.y += __shfl_xor(acc1.y, o);
        acc1.z += __shfl_xor(acc1.z, o); acc1.w += __shfl_xor(acc1.w, o);
    }
    if ((t & 48) == 0) {
        int w = t >> 6;
        redw[0][w][dq] = acc0;
        redw[1][w][dq] = acc1;
    }
    __syncthreads();

    // ---- combine + squash (wave 0, lanes 0-31: 16 lanes per bh) ----
    if (t < 32) {
        int bh = t >> 4, q = t & 15;
        float4 r0 = redw[bh][0][q], r1 = redw[bh][1][q];
        float4 r2 = redw[bh][2][q], r3 = redw[bh][3][q];
        float4 o;
        o.x = r0.x + r1.x + r2.x + r3.x;
        o.y = r0.y + r1.y + r2.y + r3.y;
        o.z = r0.z + r1.z + r2.z + r3.z;
        o.w = r0.w + r1.w + r2.w + r3.w;
        float T2 = tpar[bh][0] + tpar[bh][1];
        float4 p14 = ((const float4*)PE1)[n * 16 + q];
        o.x = fmaf(p14.x, T2, o.x);
        o.y = fmaf(p14.y, T2, o.y);
        o.z = fmaf(p14.z, T2, o.z);
        o.w = fmaf(p14.w, T2, o.w);
        outs4[bh][q] = o;
        float ssq = o.x * o.x + o.y * o.y + o.z * o.z + o.w * o.w;
        float ppu = o.x * p14.x + o.y * p14.y + o.z * p14.z + o.w * p14.w;
#pragma unroll
        for (int o2 = 1; o2 <= 8; o2 <<= 1) {   // stays within 16-lane group
            ssq += __shfl_xor(ssq, o2);
            ppu += __shfl_xor(ppu, o2);
        }
        if (q == 0) {
            sc2[bh][0] = ssq / (1.f + ssq) * rsqrtf(ssq + 1e-7f);
            sc2[bh][1] = ppu;
        }
    }
    __syncthreads();

    if (last) {
        if (t < 32) {
            int bh = t >> 4, q = t & 15;
            float sc = sc2[bh][0];
            float4 o = outs4[bh][q];
            o.x *= sc; o.y *= sc; o.z *= sc; o.w *= sc;
            ((float4*)og)[((b0 + bh) * NC + n) * 16 + q] = o;
        }
        return;
    }

    // ---- pass 2: bl[s] = scale*(sum_d outp*(M+pe2) + PUu*U[s]) ----
    float4 oa = outs4[0][dq], ob = outs4[1][dq];
#pragma unroll
    for (int i = 0; i < 8; ++i) {
        int s = s0 + i;
        float4 v0 = va[i], v1 = vb[i];
        red2[0][s * 17 + dq] = v0.x * oa.x + v0.y * oa.y + v0.z * oa.z + v0.w * oa.w;
        red2[1][s * 17 + dq] = v1.x * ob.x + v1.y * ob.y + v1.z * ob.z + v1.w * ob.w;
    }
    __syncthreads();
    {
        int bh = t >> 7, s = t & 127;
        const float* r = &red2[bh][s * 17];
        float sum = 0.f;
#pragma unroll
        for (int q = 0; q < 16; ++q) sum += r[q];
        bl[((b0 + bh) * NC + n) * NS + s] =
            sc2[bh][0] * (sum + sc2[bh][1] * Us[s][bh]);
    }
}

// ---------------------------------------------------------------------------
// kS: softmax over n for each (b,s); c[b,n,s] = softmax_n(bl[b,n,s])*mask.
// bl/c layout [b][n][s]. Block = (b, 16-s tile), 256 thr. grid = 256.
// ---------------------------------------------------------------------------
__global__ __launch_bounds__(256) void kS(const float* __restrict__ bl,
                                          const float* __restrict__ mask,
                                          float* __restrict__ c) {
    int blk = blockIdx.x;
    int b = blk >> 3, s0 = (blk & 7) * 16;
    int t = threadIdx.x;

    __shared__ float tl[NC][17];
    __shared__ float pr[16][17];
    __shared__ float ps[16][17];
    __shared__ float itot[16], msk[16];

    if (t < 16) msk[t] = mask[b * NS + s0 + t];
#pragma unroll
    for (int i = 0; i < 8; ++i) {
        int idx = i * 256 + t;
        int n = idx >> 4, si = idx & 15;
        tl[n][si] = bl[(b * NC + n) * NS + s0 + si];
    }
    __syncthreads();

    int si = t & 15, ch = t >> 4;      // 16 chunks x 8 n each
    float mx = -1e30f;
#pragma unroll
    for (int j = 0; j < 8; ++j) mx = fmaxf(mx, tl[ch * 8 + j][si]);
    pr[ch][si] = mx;
    __syncthreads();

    mx = pr[0][si];
#pragma unroll
    for (int jc = 1; jc < 16; ++jc) mx = fmaxf(mx, pr[jc][si]);
    float sm = 0.f;
#pragma unroll
    for (int j = 0; j < 8; ++j) {
        float e = __expf(tl[ch * 8 + j][si] - mx);
        tl[ch * 8 + j][si] = e;       // owner-exclusive rows: no race
        sm += e;
    }
    ps[ch][si] = sm;
    __syncthreads();

    if (t < 16) {
        float tot = 0.f;
#pragma unroll
        for (int jc = 0; jc < 16; ++jc) tot += ps[jc][t];
        itot[t] = msk[t] / tot;
    }
    __syncthreads();

#pragma unroll
    for (int i = 0; i < 8; ++i) {
        int idx = i * 256 + t;
        int n = idx >> 4, sj = idx & 15;
        c[(b * NC + n) * NS + s0 + sj] = tl[n][sj] * itot[sj];
    }
}

// ---------------------------------------------------------------------------
extern "C" void kernel_launch(void* const* d_in, const int* in_sizes, int n_in,
                              void* d_out, int out_size, void* d_ws, size_t ws_size,
                              hipStream_t stream) {
    const float* u    = (const float*)d_in[0];  // (32,128,256)
    const float* mask = (const float*)d_in[1];  // (32,128)
    const float* W    = (const float*)d_in[2];  // (1,256,64)
    float* out = (float*)d_out;                 // (32,128,64) = [b][n][d]

    float* ws  = (float*)d_ws;
    float* M   = ws;                            // 262144
    float* U   = M + NB * NS * ND;              // 4096
    float* PE1 = U + NB * NS;                   // 8192
    float* c   = PE1 + NC * ND;                 // 524288  [b][n][s]
    float* bl  = c + NB * NC * NS;              // 524288  [b][n][s]

    k_prep<<<1056, 256, 0, stream>>>(u, W, M, U, PE1);

    // iter 0 (uniform c = mask/128) -> logits bl
    kR<<<2048, 256, 0, stream>>>(M, U, PE1, c, mask, out, bl, 1, 0);
    kS<<<NB * 8, 256, 0, stream>>>(bl, mask, c);
    // iter 1 -> logits bl
    kR<<<2048, 256, 0, stream>>>(M, U, PE1, c, mask, out, bl, 0, 0);
    kS<<<NB * 8, 256, 0, stream>>>(bl, mask, c);
    // iter 2 (final) -> d_out
    kR<<<2048, 256, 0, stream>>>(M, U, PE1, c, mask, out, bl, 0, 1);
}